// Round 10
// baseline (122.387 us; speedup 1.0000x reference)
//
#include <hip/hip_runtime.h>
#include <stdint.h>

#define BATCH 32768
#define TANH_C 2.8853900817779268f   // 2/ln(2)

typedef __attribute__((ext_vector_type(8))) short short8;
typedef __attribute__((ext_vector_type(2))) float f32x2;
typedef __attribute__((ext_vector_type(4))) float f32x4;
typedef __attribute__((ext_vector_type(16))) float f32x16;
typedef __attribute__((ext_vector_type(4))) unsigned int u32x4;

__device__ __forceinline__ uint16_t bf16_rtne(float f) {
    union { float f; uint32_t u; } v; v.f = f;
    uint32_t u = v.u;
    u += 0x7fffu + ((u >> 16) & 1u);
    return (uint16_t)(u >> 16);
}

__device__ __forceinline__ uint32_t pack2_bf16(float a, float b) {
    return (uint32_t)bf16_rtne(a) | ((uint32_t)bf16_rtne(b) << 16);
}

// round-to-nearest (half-up) bf16 pack: 2x v_add_u32 + 1x v_perm_b32
__device__ __forceinline__ uint32_t pack2_bf16_fast(float a, float b) {
    uint32_t ra = __builtin_bit_cast(uint32_t, a) + 0x8000u;
    uint32_t rb = __builtin_bit_cast(uint32_t, b) + 0x8000u;
#if defined(__has_builtin)
#if __has_builtin(__builtin_amdgcn_perm)
    return __builtin_amdgcn_perm(rb, ra, 0x07060302u);  // {rb.hi16, ra.hi16}
#else
    return (rb & 0xffff0000u) | (ra >> 16);
#endif
#else
    return (rb & 0xffff0000u) | (ra >> 16);
#endif
}

__device__ __forceinline__ float fast_tanh(float x) {
    float e = __builtin_amdgcn_exp2f(x * TANH_C);
    return 1.0f - 2.0f * __builtin_amdgcn_rcpf(1.0f + e);
}

// ---------- kernel P: per-feature-d pack of B = W2g (bf16, 32x32x16 MFMA B order) ----
// W2g[k=d*64+j][n] = sum_o W2[d,j,o] * Wg1[d*64+o, n]
// B-frag for (d, chunk c, n-tile t): lane L holds k = d*64+c*16+(L>>5)*8+j, n = t*32+(L&31).
// flat u32x4 index = ((d*4+c)*2+t)*64 + ((k>>3)&1)*32 + (n&31)
// Also emits cgpart[d][n] into d_out scratch.
__global__ __launch_bounds__(512) void kol_pack(const float* __restrict__ W2,
                                                const float* __restrict__ Wg1,
                                                const float* __restrict__ b2,
                                                uint16_t* __restrict__ Bp,
                                                float* __restrict__ cgpart) {
    __shared__ __align__(16) float w2t[64 * 65];  // [o][j], stride 65
    __shared__ __align__(16) float g1s[64 * 64];  // [o][n]

    const int t = threadIdx.x;
    const int d = blockIdx.x;

    for (int f = t * 4; f < 4096; f += 2048) {
        float4 v = *(const float4*)&W2[(size_t)d * 4096 + f];
        int j = f >> 6, o = f & 63;   // W2[d][j][o..o+3]
        w2t[(o + 0) * 65 + j] = v.x;
        w2t[(o + 1) * 65 + j] = v.y;
        w2t[(o + 2) * 65 + j] = v.z;
        w2t[(o + 3) * 65 + j] = v.w;
        *(float4*)&g1s[f] = *(const float4*)&Wg1[(size_t)d * 4096 + f];
    }
    __syncthreads();

    const int jg = t >> 6;   // j-octet: k = d*64 + jg*8 + jj
    const int n  = t & 63;
    float acc[8];
#pragma unroll
    for (int i = 0; i < 8; ++i) acc[i] = 0.f;

#pragma unroll 4
    for (int o = 0; o < 64; ++o) {
        float g = g1s[o * 64 + n];
        const float* w = &w2t[o * 65 + jg * 8];
#pragma unroll
        for (int jj = 0; jj < 8; ++jj) acc[jj] = fmaf(w[jj], g, acc[jj]);
    }

    u32x4 pk;
    pk.x = pack2_bf16(acc[0], acc[1]);
    pk.y = pack2_bf16(acc[2], acc[3]);
    pk.z = pack2_bf16(acc[4], acc[5]);
    pk.w = pack2_bf16(acc[6], acc[7]);
    // c = jg>>1, hi = jg&1, tile = n>>5
    int off = ((d * 4 + (jg >> 1)) * 2 + (n >> 5)) * 64 + ((jg & 1) << 5) + (n & 31);
    ((u32x4*)Bp)[off] = pk;

    if (t < 64) {
        float a = 0.f;
        const float* b2d = &b2[(size_t)d * 64];
#pragma unroll 4
        for (int o = 0; o < 64; ++o)
            a = fmaf(b2d[o], g1s[o * 64 + t], a);
        cgpart[d * 64 + t] = a;
    }
}

// ---------- kernel R: cg[n] = bg1[n] + sum_d cgpart[d][n] ----------
__global__ __launch_bounds__(256) void kol_reduce_cg(const float* __restrict__ cgpart,
                                                     const float* __restrict__ bg1,
                                                     float* __restrict__ cg) {
    __shared__ float red[4][64];
    const int t = threadIdx.x;
    const int n = t & 63, seg = t >> 6;
    float a = 0.f;
#pragma unroll 4
    for (int d = seg * 16; d < seg * 16 + 16; ++d)
        a += cgpart[d * 64 + n];
    red[seg][n] = a;
    __syncthreads();
    if (t < 64)
        cg[n] = bg1[n] + red[0][n] + red[1][n] + red[2][n] + red[3][n];
}

// ---------- kernel M: main fused GEMM, 32x32x16 MFMA, M=32/wave, K-split x4 ----------
// 512 thr = 8 waves = 2 row-groups(32 rows) x 4 K-quarters(16 d). 64 rows/block,
// 512 blocks. amdgpu_waves_per_eu(1,2) licenses a ~256-VGPR budget so the
// scheduler can (a) keep the explicit 2-stage B pipeline live and (b) interleave
// the 16 independent tanh chains (phase-structured below) at trans-unit
// throughput instead of serializing them to save registers.
__global__ __launch_bounds__(512)
__attribute__((amdgpu_waves_per_eu(1, 2)))
void kol_main(
    const float* __restrict__ x, const float* __restrict__ W1, const float* __restrict__ b1,
    const uint16_t* __restrict__ Bp, const float* __restrict__ cg,
    const float* __restrict__ Wg2, const float* __restrict__ bg2f,
    float* __restrict__ out) {
    __shared__ __align__(16) float smem[12544];   // 50176 B
    float* xs  = smem;            // 64*68 = 4352 floats, pre-scaled x
    float* w1s = smem + 4352;     // 4096
    float* b1s = smem + 8448;     // 4096, pre-scaled by TANH_C
    // combine overlay (after main loop): f32x4 cmb[8][6][64] = 49152 B over smem

    const int tid = threadIdx.x;
    const int wave = tid >> 6, lane = tid & 63;
    const int nn = lane & 31, hi = lane >> 5;
    const int rg = wave & 1, kq = wave >> 1;
    const int rowbase = blockIdx.x * 64;

#pragma unroll
    for (int ff = 0; ff < 2; ++ff) {
        int f = tid * 4 + ff * 2048;
        int r = f >> 6, c = f & 63;
        float4 v = *(const float4*)&x[(size_t)(rowbase + r) * 64 + c];
        v.x *= TANH_C; v.y *= TANH_C; v.z *= TANH_C; v.w *= TANH_C;
        *(float4*)&xs[r * 68 + c] = v;
        *(float4*)&w1s[f] = *(const float4*)&W1[f];
        float4 b = *(const float4*)&b1[f];
        b.x *= TANH_C; b.y *= TANH_C; b.z *= TANH_C; b.w *= TANH_C;
        *(float4*)&b1s[f] = b;
    }
    __syncthreads();

    f32x16 acc0, acc1;
#pragma unroll
    for (int i = 0; i < 16; ++i) { acc0[i] = 0.f; acc1[i] = 0.f; }

    const u32x4* bp = (const u32x4*)Bp + lane;
    const float* xcol = &xs[(rg * 32 + nn) * 68];

    // prime the 2-stage pipeline with d = kq*16
    u32x4 bcur[8];
    {
        const u32x4* bfp0 = bp + (size_t)(kq * 16) * 512;
#pragma unroll
        for (int i = 0; i < 8; ++i) bcur[i] = bfp0[i * 64];
    }

#pragma unroll 1
    for (int dd = 0; dd < 16; ++dd) {
        const int d = kq * 16 + dd;

        // issue next iteration's 8 B-fragment loads (hidden by tanh phases)
        u32x4 bnxt[8];
        const u32x4* bfpn = bp + (size_t)(kq * 16 + ((dd + 1) & 15)) * 512;
#pragma unroll
        for (int i = 0; i < 8; ++i) bnxt[i] = bfpn[i * 64];

        const float xv = xcol[d];
        const f32x2 xvv = { xv, xv };

        // phase 0: all 16 LDS loads up front
        float4 wv[8], bw[8];
#pragma unroll
        for (int c = 0; c < 4; ++c) {
            const float* wq = &w1s[d * 64 + c * 16 + hi * 8];
            const float* bq = &b1s[d * 64 + c * 16 + hi * 8];
            wv[2 * c]     = *(const float4*)&wq[0];
            wv[2 * c + 1] = *(const float4*)&wq[4];
            bw[2 * c]     = *(const float4*)&bq[0];
            bw[2 * c + 1] = *(const float4*)&bq[4];
        }

        // phase A: 16 packed args (v_pk_fma_f32) + 32 exp2 — independent chains
        f32x2 e[16];
#pragma unroll
        for (int i = 0; i < 8; ++i) {
            f32x2 w0 = { wv[i].x, wv[i].y }, b0 = { bw[i].x, bw[i].y };
            f32x2 w1v = { wv[i].z, wv[i].w }, b1v = { bw[i].z, bw[i].w };
            f32x2 a0 = w0 * xvv + b0;
            f32x2 a1 = w1v * xvv + b1v;
            e[2 * i]     = (f32x2){ __builtin_amdgcn_exp2f(a0.x), __builtin_amdgcn_exp2f(a0.y) };
            e[2 * i + 1] = (f32x2){ __builtin_amdgcn_exp2f(a1.x), __builtin_amdgcn_exp2f(a1.y) };
        }

        // phase B: 16 shared-rcp finishes + packs — independent chains
        uint32_t au[16];
#pragma unroll
        for (int i = 0; i < 16; ++i) {
            f32x2 dn = e[i] + 1.0f;
            float ir = __builtin_amdgcn_rcpf(dn.x * dn.y);
            float m  = -2.0f * ir;
            float hx = fmaf(dn.y, m, 1.0f);
            float hy = fmaf(dn.x, m, 1.0f);
            au[i] = pack2_bf16_fast(hx, hy);
        }

        // phase C: 8 MFMAs
#pragma unroll
        for (int c = 0; c < 4; ++c) {
            union { uint32_t u[4]; short8 s; } a;
            a.u[0] = au[4 * c + 0]; a.u[1] = au[4 * c + 1];
            a.u[2] = au[4 * c + 2]; a.u[3] = au[4 * c + 3];
            union { u32x4 u; short8 s; } b0c, b1c;
            b0c.u = bcur[c * 2 + 0];
            b1c.u = bcur[c * 2 + 1];
            acc0 = __builtin_amdgcn_mfma_f32_32x32x16_bf16(a.s, b0c.s, acc0, 0, 0, 0);
            acc1 = __builtin_amdgcn_mfma_f32_32x32x16_bf16(a.s, b1c.s, acc1, 0, 0, 0);
        }
#pragma unroll
        for (int i = 0; i < 8; ++i) bcur[i] = bnxt[i];
    }

    // ---- combine 4 K-quarter partials through LDS (smem dead) ----
    __syncthreads();
    f32x4* cmb = (f32x4*)smem;   // [s 0..7][widx 0..5][lane]
    if (kq != 0) {
        const int widx = (kq - 1) * 2 + rg;
#pragma unroll
        for (int s = 0; s < 8; ++s) {
            const int base = (s & 3) * 4;
            f32x4 v;
            if (s < 4) v = (f32x4){acc0[base], acc0[base + 1], acc0[base + 2], acc0[base + 3]};
            else       v = (f32x4){acc1[base], acc1[base + 1], acc1[base + 2], acc1[base + 3]};
            cmb[(s * 6 + widx) * 64 + lane] = v;
        }
    }
    __syncthreads();

    if (kq == 0) {
#pragma unroll
        for (int s = 0; s < 8; ++s) {
            const int base = (s & 3) * 4;
            f32x4 v0 = cmb[(s * 6 + 0 + rg) * 64 + lane];
            f32x4 v1 = cmb[(s * 6 + 2 + rg) * 64 + lane];
            f32x4 v2 = cmb[(s * 6 + 4 + rg) * 64 + lane];
            f32x4 v = v0 + v1 + v2;
            if (s < 4) {
#pragma unroll
                for (int i = 0; i < 4; ++i) acc0[base + i] += v[i];
            } else {
#pragma unroll
                for (int i = 0; i < 4; ++i) acc1[base + i] += v[i];
            }
        }
        // epilogue: out[b] = bg2 + sum_n Wg2[n]*tanh(C[b,n]+cg[n])
        // C/D map: col = t*32+nn, row m = (r&3) + 8*(r>>2) + 4*hi
        const float cg0 = cg[nn],      cg1 = cg[32 + nn];
        const float wg0 = Wg2[nn],     wg1 = Wg2[32 + nn];
        const float bg2 = bg2f[0];
#pragma unroll
        for (int g = 0; g < 4; ++g) {
            float4 res;
#pragma unroll
            for (int rr = 0; rr < 4; ++rr) {
                const int r = g * 4 + rr;
                float s = wg0 * fast_tanh(acc0[r] + cg0) + wg1 * fast_tanh(acc1[r] + cg1);
                s += __shfl_xor(s, 1, 64);
                s += __shfl_xor(s, 2, 64);
                s += __shfl_xor(s, 4, 64);
                s += __shfl_xor(s, 8, 64);
                s += __shfl_xor(s, 16, 64);
                ((float*)&res)[rr] = s + bg2;
            }
            if (nn == 0)
                *(float4*)&out[rowbase + rg * 32 + 8 * g + 4 * hi] = res;
        }
    }
}

extern "C" void kernel_launch(void* const* d_in, const int* in_sizes, int n_in,
                              void* d_out, int out_size, void* d_ws, size_t ws_size,
                              hipStream_t stream) {
    const float* x   = (const float*)d_in[0];
    const float* W1  = (const float*)d_in[1];
    const float* b1  = (const float*)d_in[2];
    const float* W2  = (const float*)d_in[3];
    const float* b2  = (const float*)d_in[4];
    const float* Wg1 = (const float*)d_in[5];
    const float* bg1 = (const float*)d_in[6];
    const float* Wg2 = (const float*)d_in[7];
    const float* bg2 = (const float*)d_in[8];
    float* out = (float*)d_out;

    // ws: Bp 512KB + cg 256B (proven budget). cgpart (16KB) in d_out:
    // written by kol_pack, read by kol_reduce_cg, fully overwritten by kol_main.
    uint16_t* Bp  = (uint16_t*)d_ws;
    float* cg     = (float*)((char*)d_ws + 4096 * 64 * 2);
    float* cgpart = out;

    kol_pack<<<64, 512, 0, stream>>>(W2, Wg1, b2, Bp, cgpart);
    kol_reduce_cg<<<1, 256, 0, stream>>>(cgpart, bg1, cg);
    kol_main<<<BATCH / 64, 512, 0, stream>>>(x, W1, b1, Bp, cg, Wg2, bg2, out);
}